// Round 5
// baseline (96.692 us; speedup 1.0000x reference)
//
#include <hip/hip_runtime.h>
#include <math.h>

// PartialChamferLoss: B=2, N=8192, M=32768, S=4096.
// d2 = |x|^2 + |y|^2 - 2 x.y ; min over M per query ; mean(sqrt).
// R5: single fused kernel + 32KB memset. Targets register-resident (R=32,
// 2048/wave), queries rotate via shared SoA LDS ring, traveling min via
// ds_bpermute consumed at END of next step (latency-hidden). Block folds
// 4 waves' mins in LDS, 64 global atomicMins/block; last block (ticket)
// re-reads mins coherently, computes mean(sqrt) -> d_out. 2 dispatches.
typedef float vf2 __attribute__((ext_vector_type(2)));

constexpr int B = 2;
constexpr int N = 8192;
constexpr int M = 32768;
constexpr int S = 4096;
constexpr int QTOT = B * S;          // 8192 queries
constexpr int R = 32;                // targets per lane
constexpr int WT = 64 * R;           // 2048 targets per wave
constexpr int TCH = M / WT;          // 16 target chunks per batch
constexpr int QG = S / 64;           // 64 query groups per batch
constexpr int WAVES = B * TCH * QG;  // 2048 waves
constexpr int BLOCKS = WAVES / 4;    // 512 blocks x 256 threads

// ws layout: [0,32KB): 8192 u32 min-bits; [32KB,32KB+4): ticket counter.
// Both memset to 0xFF: 0xFFFFFFFF > any float bits we write (uint min ok);
// counter tickets wrap from 0xFFFFFFFF so the 512th arrival reads 510.

__global__ __launch_bounds__(256, 2) void chamfer_main(
    const float* __restrict__ pred, const float* __restrict__ target,
    const int* __restrict__ idx, unsigned* __restrict__ wsmin,
    unsigned* __restrict__ ticket, float* __restrict__ out) {
  __shared__ float qs0[64], qs1[64], qs2[64], qw[64];  // SoA query records
  __shared__ unsigned qmin[64];                        // block-level min fold
  __shared__ int islast;
  const int lane = threadIdx.x & 63;
  const int w = blockIdx.x * 4 + (threadIdx.x >> 6);  // 0..2047
  const int b = w >> 10;
  const int rem = w & 1023;
  const int tch = rem & (TCH - 1);  // varies across block's 4 waves
  const int qg = rem >> 4;          // uniform across block (4 | TCH)

  // Gather this block's query group directly from pred[idx] (L2-hot).
  if (threadIdx.x < 64) {
    int s = qg * 64 + threadIdx.x;
    int i = idx[s];
    const float* p = pred + ((size_t)b * N + (size_t)i) * 3;
    float x = p[0], y = p[1], z = p[2];
    qs0[threadIdx.x] = -2.0f * x;
    qs1[threadIdx.x] = -2.0f * y;
    qs2[threadIdx.x] = -2.0f * z;
    qw[threadIdx.x] = x * x + y * y + z * z;
    qmin[threadIdx.x] = 0xFFFFFFFFu;
  }

  // Stage this lane's 32 targets as 16 float2-pairs (pk_fma operands).
  const float* tb = target + ((size_t)b * M + (size_t)tch * WT) * 3;
  vf2 t0p[16], t1p[16], t2p[16], ty2p[16];
#pragma unroll
  for (int p = 0; p < 16; ++p) {
    int mA = (2 * p) * 64 + lane;
    int mB = (2 * p + 1) * 64 + lane;
    float ax = tb[3 * mA], ay = tb[3 * mA + 1], az = tb[3 * mA + 2];
    float bx = tb[3 * mB], by = tb[3 * mB + 1], bz = tb[3 * mB + 2];
    t0p[p] = vf2{ax, bx};
    t1p[p] = vf2{ay, by};
    t2p[p] = vf2{az, bz};
    ty2p[p] = vf2{fmaf(ax, ax, fmaf(ay, ay, az * az)),
                  fmaf(bx, bx, fmaf(by, by, bz * bz))};
  }
  __syncthreads();

  const float qx2_home = qw[lane];        // own |x|^2, applied at the end
  const int rot = ((lane + 1) & 63) * 4;  // bpermute byte-addr: pull lane+1
  float mm = INFINITY;                    // traveling min of (|y|^2 - 2x.y)
  int qoff = lane;
  float q0 = qs0[qoff], q1 = qs1[qoff], q2 = qs2[qoff];

  for (int step = 0; step < 64; ++step) {
    // Prefetch next query (LDS latency hides under the 16-pair compute).
    int qn = (qoff + 1) & 63;
    float n0 = qs0[qn], n1 = qs1[qn], n2 = qs2[qn];
    vf2 Q0 = vf2{q0, q0}, Q1 = vf2{q1, q1}, Q2 = vf2{q2, q2};
    float m0 = INFINITY, m1 = INFINITY;
#pragma unroll
    for (int p = 0; p < 16; p += 2) {
      vf2 s = __builtin_elementwise_fma(Q0, t0p[p], ty2p[p]);
      s = __builtin_elementwise_fma(Q1, t1p[p], s);
      s = __builtin_elementwise_fma(Q2, t2p[p], s);
      m0 = fminf(fminf(s.x, s.y), m0);  // v_min3_f32
      vf2 u = __builtin_elementwise_fma(Q0, t0p[p + 1], ty2p[p + 1]);
      u = __builtin_elementwise_fma(Q1, t1p[p + 1], u);
      u = __builtin_elementwise_fma(Q2, t2p[p + 1], u);
      m1 = fminf(fminf(u.x, u.y), m1);
    }
    // Incoming traveling min (prev step's bpermute) consumed only here.
    mm = fminf(mm, fminf(m0, m1));
    mm = __int_as_float(__builtin_amdgcn_ds_bpermute(rot, __float_as_int(mm)));
    q0 = n0; q1 = n1; q2 = n2; qoff = qn;
  }
  // After 64 rotations the own query's complete chunk-min is back home.
  atomicMin(&qmin[lane], __float_as_uint(fmaxf(qx2_home + mm, 0.0f)));
  __syncthreads();

  // One wave publishes the block's folded mins; then take a ticket.
  if (threadIdx.x < 64) {
    int q = b * S + qg * 64 + threadIdx.x;
    atomicMin(&wsmin[q], qmin[threadIdx.x]);
    __threadfence();
  }
  __syncthreads();
  if (threadIdx.x == 0) {
    unsigned t = atomicAdd(ticket, 1u);  // starts at 0xFFFFFFFF (memset 0xFF)
    islast = (t == (unsigned)(BLOCKS - 2));  // 512th arrival reads 510
  }
  __syncthreads();
  if (!islast) return;

  // Last block: coherent re-read of all mins, mean(sqrt) -> out.
  float sum = 0.0f;
  for (int q = threadIdx.x; q < QTOT; q += 256)
    sum += sqrtf(__uint_as_float(atomicAdd(&wsmin[q], 0u)));
#pragma unroll
  for (int off = 32; off > 0; off >>= 1)
    sum += __shfl_down(sum, off, 64);
  __shared__ float red[4];
  int wv = threadIdx.x >> 6;
  if ((threadIdx.x & 63) == 0) red[wv] = sum;
  __syncthreads();
  if (threadIdx.x == 0)
    out[0] = (red[0] + red[1] + red[2] + red[3]) / (float)QTOT;
}

extern "C" void kernel_launch(void* const* d_in, const int* in_sizes, int n_in,
                              void* d_out, int out_size, void* d_ws, size_t ws_size,
                              hipStream_t stream) {
  const float* pred = (const float*)d_in[0];
  const float* target = (const float*)d_in[1];
  const int* idx = (const int*)d_in[2];
  unsigned* wsmin = (unsigned*)d_ws;
  unsigned* ticket = wsmin + QTOT;

  hipMemsetAsync(d_ws, 0xFF, QTOT * sizeof(unsigned) + 4, stream);
  chamfer_main<<<BLOCKS, 256, 0, stream>>>(pred, target, idx, wsmin, ticket,
                                           (float*)d_out);
}

// Round 6
// 90.405 us; speedup vs baseline: 1.0695x; 1.0695x over previous
//
#include <hip/hip_runtime.h>
#include <math.h>

// PartialChamferLoss: B=2, N=8192, M=32768, S=4096.
// d2 = |x|^2 + |y|^2 - 2 x.y ; min over M per query ; mean(sqrt).
// R6: SPILL FIX. R5 showed VGPR=76 (target arrays spilled to scratch ->
// 1 block/CU, 42us main). Targets now in MACRO-NAMED vf2 registers (no
// arrays, SROA guaranteed), R=16/lane (64 floats + ~30 working ~ 100 VGPR).
// Queries rotate via LDS SoA ring; traveling min via ds_bpermute; fused
// last-block (ticket) mean(sqrt) epilogue. ws init: one 32KB memset 0xFF.
typedef float vf2 __attribute__((ext_vector_type(2)));

constexpr int B = 2;
constexpr int N = 8192;
constexpr int M = 32768;
constexpr int S = 4096;
constexpr int QTOT = B * S;          // 8192 queries
constexpr int R = 16;                // targets per lane (NO spill at 16)
constexpr int WT = 64 * R;           // 1024 targets per wave
constexpr int TCH = M / WT;          // 32 target chunks per batch
constexpr int QG = S / 64;           // 64 query groups per batch
constexpr int WAVES = B * TCH * QG;  // 4096 waves
constexpr int BLOCKS = WAVES / 4;    // 1024 blocks x 256 threads

// ws layout: [0,32KB): 8192 u32 min-bits; [32KB,32KB+4): ticket counter.
// Both memset 0xFF: 0xFFFFFFFF > any clamped-min bits (uint atomicMin safe);
// ticket wraps from 0xFFFFFFFF so the 512th..1024th arrival reads BLOCKS-2.

#define DECLP(j) vf2 T0_##j, T1_##j, T2_##j, TY_##j;
#define LOADP(j)                                                         \
  {                                                                      \
    int mA = (2 * j) * 64 + lane, mB = (2 * j + 1) * 64 + lane;          \
    float ax = tb[3 * mA], ay = tb[3 * mA + 1], az = tb[3 * mA + 2];     \
    float bx = tb[3 * mB], by = tb[3 * mB + 1], bz = tb[3 * mB + 2];     \
    T0_##j = vf2{ax, bx};                                                \
    T1_##j = vf2{ay, by};                                                \
    T2_##j = vf2{az, bz};                                                \
    TY_##j = vf2{fmaf(ax, ax, fmaf(ay, ay, az * az)),                    \
                 fmaf(bx, bx, fmaf(by, by, bz * bz))};                   \
  }
#define PAIRC(j, acc)                                                    \
  {                                                                      \
    vf2 s = __builtin_elementwise_fma(Q0, T0_##j, TY_##j);               \
    s = __builtin_elementwise_fma(Q1, T1_##j, s);                        \
    s = __builtin_elementwise_fma(Q2, T2_##j, s);                        \
    acc = fminf(fminf(s.x, s.y), acc); /* v_min3_f32 */                  \
  }

__global__ __launch_bounds__(256) void chamfer_main(
    const float* __restrict__ pred, const float* __restrict__ target,
    const int* __restrict__ idx, unsigned* __restrict__ wsmin,
    unsigned* __restrict__ ticket, float* __restrict__ out) {
  __shared__ float qs0[64], qs1[64], qs2[64], qw[64];  // SoA query records
  __shared__ unsigned qmin[64];                        // block-level min fold
  __shared__ int islast;
  const int lane = threadIdx.x & 63;
  const int w = blockIdx.x * 4 + (threadIdx.x >> 6);  // 0..4095
  const int b = w >> 11;
  const int rem = w & 2047;
  const int tch = rem & (TCH - 1);  // varies across block's 4 waves
  const int qg = rem >> 5;          // uniform across block (4 | TCH)

  // Gather this block's query group directly from pred[idx] (L2-hot).
  if (threadIdx.x < 64) {
    int s = qg * 64 + threadIdx.x;
    int i = idx[s];
    const float* p = pred + ((size_t)b * N + (size_t)i) * 3;
    float x = p[0], y = p[1], z = p[2];
    qs0[threadIdx.x] = -2.0f * x;
    qs1[threadIdx.x] = -2.0f * y;
    qs2[threadIdx.x] = -2.0f * z;
    qw[threadIdx.x] = x * x + y * y + z * z;
    qmin[threadIdx.x] = 0xFFFFFFFFu;
  }

  // Stage this lane's 16 targets into NAMED registers (8 float2-pairs).
  const float* tb = target + ((size_t)b * M + (size_t)tch * WT) * 3;
  DECLP(0) DECLP(1) DECLP(2) DECLP(3) DECLP(4) DECLP(5) DECLP(6) DECLP(7)
  LOADP(0) LOADP(1) LOADP(2) LOADP(3) LOADP(4) LOADP(5) LOADP(6) LOADP(7)
  __syncthreads();

  const float qx2_home = qw[lane];        // own |x|^2, applied at the end
  const int rot = ((lane + 1) & 63) * 4;  // bpermute byte-addr: pull lane+1
  float mm = INFINITY;                    // traveling min of (|y|^2 - 2x.y)
  int qoff = lane;
  float q0 = qs0[qoff], q1 = qs1[qoff], q2 = qs2[qoff];

  for (int step = 0; step < 64; ++step) {
    // Prefetch next query (LDS latency hides under the 8-pair compute).
    int qn = (qoff + 1) & 63;
    float n0 = qs0[qn], n1 = qs1[qn], n2 = qs2[qn];
    vf2 Q0 = vf2{q0, q0}, Q1 = vf2{q1, q1}, Q2 = vf2{q2, q2};
    float m0 = INFINITY, m1 = INFINITY;
    PAIRC(0, m0) PAIRC(1, m1) PAIRC(2, m0) PAIRC(3, m1)
    PAIRC(4, m0) PAIRC(5, m1) PAIRC(6, m0) PAIRC(7, m1)
    // Incoming traveling min (prev step's bpermute) consumed only here.
    mm = fminf(mm, fminf(m0, m1));
    mm = __int_as_float(__builtin_amdgcn_ds_bpermute(rot, __float_as_int(mm)));
    q0 = n0; q1 = n1; q2 = n2; qoff = qn;
  }
  // After 64 rotations the own query's complete chunk-min is back home.
  atomicMin(&qmin[lane], __float_as_uint(fmaxf(qx2_home + mm, 0.0f)));
  __syncthreads();

  // One wave publishes the block's folded mins; then take a ticket.
  if (threadIdx.x < 64) {
    int q = b * S + qg * 64 + threadIdx.x;
    atomicMin(&wsmin[q], qmin[threadIdx.x]);
    __threadfence();
  }
  __syncthreads();
  if (threadIdx.x == 0) {
    unsigned t = atomicAdd(ticket, 1u);  // starts at 0xFFFFFFFF (memset 0xFF)
    islast = (t == (unsigned)(BLOCKS - 2));  // final arrival reads BLOCKS-2
  }
  __syncthreads();
  if (!islast) return;

  // Last block: coherent re-read of all mins, mean(sqrt) -> out.
  // 4 independent accumulators pipeline the atomic-read latencies.
  float s0 = 0.0f, s1 = 0.0f, s2 = 0.0f, s3 = 0.0f;
  for (int i = 0; i < QTOT / 256; i += 4) {
    int q = threadIdx.x + i * 256;
    s0 += sqrtf(__uint_as_float(atomicAdd(&wsmin[q], 0u)));
    s1 += sqrtf(__uint_as_float(atomicAdd(&wsmin[q + 256], 0u)));
    s2 += sqrtf(__uint_as_float(atomicAdd(&wsmin[q + 512], 0u)));
    s3 += sqrtf(__uint_as_float(atomicAdd(&wsmin[q + 768], 0u)));
  }
  float sum = (s0 + s1) + (s2 + s3);
#pragma unroll
  for (int off = 32; off > 0; off >>= 1)
    sum += __shfl_down(sum, off, 64);
  __shared__ float red[4];
  int wv = threadIdx.x >> 6;
  if ((threadIdx.x & 63) == 0) red[wv] = sum;
  __syncthreads();
  if (threadIdx.x == 0)
    out[0] = (red[0] + red[1] + red[2] + red[3]) / (float)QTOT;
}

extern "C" void kernel_launch(void* const* d_in, const int* in_sizes, int n_in,
                              void* d_out, int out_size, void* d_ws, size_t ws_size,
                              hipStream_t stream) {
  const float* pred = (const float*)d_in[0];
  const float* target = (const float*)d_in[1];
  const int* idx = (const int*)d_in[2];
  unsigned* wsmin = (unsigned*)d_ws;
  unsigned* ticket = wsmin + QTOT;

  hipMemsetAsync(d_ws, 0xFF, QTOT * sizeof(unsigned) + 4, stream);
  chamfer_main<<<BLOCKS, 256, 0, stream>>>(pred, target, idx, wsmin, ticket,
                                           (float*)d_out);
}

// Round 7
// 89.553 us; speedup vs baseline: 1.0797x; 1.0095x over previous
//
#include <hip/hip_runtime.h>
#include <math.h>

// PartialChamferLoss: B=2, N=8192, M=32768, S=4096.
// d2 = |x|^2 + |y|^2 - 2 x.y ; min over M per query ; mean(sqrt).
// R7: R6 + two register-pressure safeguards. R5 measured the spill signature
// (VGPR=76+scratch, VALUBusy 14us vs 8.5 theoretical); R6's budget implied
// main ~33us (3x theory) -> suspect: compiler unrolling the 64-step loop
// (compile-time trip count) multiplies the 32 vf2 live ranges. Fix:
// #pragma unroll 1 on the step loop + __launch_bounds__(256,4) (VGPR<=128,
// 4 blocks/CU, all 1024 blocks co-resident). Structure unchanged from R6.
typedef float vf2 __attribute__((ext_vector_type(2)));

constexpr int B = 2;
constexpr int N = 8192;
constexpr int M = 32768;
constexpr int S = 4096;
constexpr int QTOT = B * S;          // 8192 queries
constexpr int R = 16;                // targets per lane
constexpr int WT = 64 * R;           // 1024 targets per wave
constexpr int TCH = M / WT;          // 32 target chunks per batch
constexpr int QG = S / 64;           // 64 query groups per batch
constexpr int WAVES = B * TCH * QG;  // 4096 waves
constexpr int BLOCKS = WAVES / 4;    // 1024 blocks x 256 threads

// ws layout: [0,32KB): 8192 u32 min-bits; [32KB,32KB+4): ticket counter.
// Both memset 0xFF: 0xFFFFFFFF > any clamped-min bits (uint atomicMin safe);
// ticket wraps from 0xFFFFFFFF so the final arrival reads BLOCKS-2.

#define DECLP(j) vf2 T0_##j, T1_##j, T2_##j, TY_##j;
#define LOADP(j)                                                         \
  {                                                                      \
    int mA = (2 * j) * 64 + lane, mB = (2 * j + 1) * 64 + lane;          \
    float ax = tb[3 * mA], ay = tb[3 * mA + 1], az = tb[3 * mA + 2];     \
    float bx = tb[3 * mB], by = tb[3 * mB + 1], bz = tb[3 * mB + 2];     \
    T0_##j = vf2{ax, bx};                                                \
    T1_##j = vf2{ay, by};                                                \
    T2_##j = vf2{az, bz};                                                \
    TY_##j = vf2{fmaf(ax, ax, fmaf(ay, ay, az * az)),                    \
                 fmaf(bx, bx, fmaf(by, by, bz * bz))};                   \
  }
#define PAIRC(j, acc)                                                    \
  {                                                                      \
    vf2 s = __builtin_elementwise_fma(Q0, T0_##j, TY_##j);               \
    s = __builtin_elementwise_fma(Q1, T1_##j, s);                        \
    s = __builtin_elementwise_fma(Q2, T2_##j, s);                        \
    acc = fminf(fminf(s.x, s.y), acc); /* v_min3_f32 */                  \
  }

__global__ __launch_bounds__(256, 4) void chamfer_main(
    const float* __restrict__ pred, const float* __restrict__ target,
    const int* __restrict__ idx, unsigned* __restrict__ wsmin,
    unsigned* __restrict__ ticket, float* __restrict__ out) {
  __shared__ float qs0[64], qs1[64], qs2[64], qw[64];  // SoA query records
  __shared__ unsigned qmin[64];                        // block-level min fold
  __shared__ int islast;
  const int lane = threadIdx.x & 63;
  const int w = blockIdx.x * 4 + (threadIdx.x >> 6);  // 0..4095
  const int b = w >> 11;
  const int rem = w & 2047;
  const int tch = rem & (TCH - 1);  // varies across block's 4 waves
  const int qg = rem >> 5;          // uniform across block (4 | TCH)

  // Gather this block's query group directly from pred[idx] (L2-hot).
  if (threadIdx.x < 64) {
    int s = qg * 64 + threadIdx.x;
    int i = idx[s];
    const float* p = pred + ((size_t)b * N + (size_t)i) * 3;
    float x = p[0], y = p[1], z = p[2];
    qs0[threadIdx.x] = -2.0f * x;
    qs1[threadIdx.x] = -2.0f * y;
    qs2[threadIdx.x] = -2.0f * z;
    qw[threadIdx.x] = x * x + y * y + z * z;
    qmin[threadIdx.x] = 0xFFFFFFFFu;
  }

  // Stage this lane's 16 targets into NAMED registers (8 float2-pairs).
  const float* tb = target + ((size_t)b * M + (size_t)tch * WT) * 3;
  DECLP(0) DECLP(1) DECLP(2) DECLP(3) DECLP(4) DECLP(5) DECLP(6) DECLP(7)
  LOADP(0) LOADP(1) LOADP(2) LOADP(3) LOADP(4) LOADP(5) LOADP(6) LOADP(7)
  __syncthreads();

  const float qx2_home = qw[lane];        // own |x|^2, applied at the end
  const int rot = ((lane + 1) & 63) * 4;  // bpermute byte-addr: pull lane+1
  float mm = INFINITY;                    // traveling min of (|y|^2 - 2x.y)
  int qoff = lane;
  float q0 = qs0[qoff], q1 = qs1[qoff], q2 = qs2[qoff];

#pragma unroll 1  // DO NOT unroll: keeps 32 vf2 target regs' live ranges tight
  for (int step = 0; step < 64; ++step) {
    // Prefetch next query (LDS latency hides under the 8-pair compute).
    int qn = (qoff + 1) & 63;
    float n0 = qs0[qn], n1 = qs1[qn], n2 = qs2[qn];
    vf2 Q0 = vf2{q0, q0}, Q1 = vf2{q1, q1}, Q2 = vf2{q2, q2};
    float m0 = INFINITY, m1 = INFINITY;
    PAIRC(0, m0) PAIRC(1, m1) PAIRC(2, m0) PAIRC(3, m1)
    PAIRC(4, m0) PAIRC(5, m1) PAIRC(6, m0) PAIRC(7, m1)
    // Incoming traveling min (prev step's bpermute) consumed only here.
    mm = fminf(mm, fminf(m0, m1));
    mm = __int_as_float(__builtin_amdgcn_ds_bpermute(rot, __float_as_int(mm)));
    q0 = n0; q1 = n1; q2 = n2; qoff = qn;
  }
  // After 64 rotations the own query's complete chunk-min is back home.
  atomicMin(&qmin[lane], __float_as_uint(fmaxf(qx2_home + mm, 0.0f)));
  __syncthreads();

  // One wave publishes the block's folded mins; then take a ticket.
  if (threadIdx.x < 64) {
    int q = b * S + qg * 64 + threadIdx.x;
    atomicMin(&wsmin[q], qmin[threadIdx.x]);
    __threadfence();
  }
  __syncthreads();
  if (threadIdx.x == 0) {
    unsigned t = atomicAdd(ticket, 1u);  // starts at 0xFFFFFFFF (memset 0xFF)
    islast = (t == (unsigned)(BLOCKS - 2));  // final arrival reads BLOCKS-2
  }
  __syncthreads();
  if (!islast) return;

  // Last block: coherent re-read of all mins, mean(sqrt) -> out.
  // 4 independent accumulators pipeline the atomic-read latencies.
  float s0 = 0.0f, s1 = 0.0f, s2 = 0.0f, s3 = 0.0f;
#pragma unroll 1
  for (int i = 0; i < QTOT / 256; i += 4) {
    int q = threadIdx.x + i * 256;
    s0 += sqrtf(__uint_as_float(atomicAdd(&wsmin[q], 0u)));
    s1 += sqrtf(__uint_as_float(atomicAdd(&wsmin[q + 256], 0u)));
    s2 += sqrtf(__uint_as_float(atomicAdd(&wsmin[q + 512], 0u)));
    s3 += sqrtf(__uint_as_float(atomicAdd(&wsmin[q + 768], 0u)));
  }
  float sum = (s0 + s1) + (s2 + s3);
#pragma unroll
  for (int off = 32; off > 0; off >>= 1)
    sum += __shfl_down(sum, off, 64);
  __shared__ float red[4];
  int wv = threadIdx.x >> 6;
  if ((threadIdx.x & 63) == 0) red[wv] = sum;
  __syncthreads();
  if (threadIdx.x == 0)
    out[0] = (red[0] + red[1] + red[2] + red[3]) / (float)QTOT;
}

extern "C" void kernel_launch(void* const* d_in, const int* in_sizes, int n_in,
                              void* d_out, int out_size, void* d_ws, size_t ws_size,
                              hipStream_t stream) {
  const float* pred = (const float*)d_in[0];
  const float* target = (const float*)d_in[1];
  const int* idx = (const int*)d_in[2];
  unsigned* wsmin = (unsigned*)d_ws;
  unsigned* ticket = wsmin + QTOT;

  hipMemsetAsync(d_ws, 0xFF, QTOT * sizeof(unsigned) + 4, stream);
  chamfer_main<<<BLOCKS, 256, 0, stream>>>(pred, target, idx, wsmin, ticket,
                                           (float*)d_out);
}

// Round 8
// 83.012 us; speedup vs baseline: 1.1648x; 1.0788x over previous
//
#include <hip/hip_runtime.h>
#include <math.h>

// PartialChamferLoss: B=2, N=8192, M=32768, S=4096.
// d2 = |x|^2 + |y|^2 - 2 x.y ; min over M per query ; mean(sqrt).
// R8: best-of-both. R5-R7 showed the fused last-block epilogue (ticket +
// per-block device __threadfence) costs ~6us net vs a separate finish
// dispatch (kernel boundary = free ordering). Revert to the R4 2-kernel
// shape, keep R7's proven no-spill K-loop: named-register targets (R=16),
// #pragma unroll 1 on the step loop, __launch_bounds__(256,4), LDS SoA
// query ring + ds_bpermute traveling min, per-block query gather, 32KB
// memset-0xFF wsmin init (0xFFFFFFFF > any clamped-min bits for uint min).
typedef float vf2 __attribute__((ext_vector_type(2)));

constexpr int B = 2;
constexpr int N = 8192;
constexpr int M = 32768;
constexpr int S = 4096;
constexpr int QTOT = B * S;          // 8192 queries
constexpr int R = 16;                // targets per lane (no spill at 16)
constexpr int WT = 64 * R;           // 1024 targets per wave
constexpr int TCH = M / WT;          // 32 target chunks per batch
constexpr int QG = S / 64;           // 64 query groups per batch
constexpr int WAVES = B * TCH * QG;  // 4096 waves
constexpr int BLOCKS = WAVES / 4;    // 1024 blocks x 256 threads

#define DECLP(j) vf2 T0_##j, T1_##j, T2_##j, TY_##j;
#define LOADP(j)                                                         \
  {                                                                      \
    int mA = (2 * j) * 64 + lane, mB = (2 * j + 1) * 64 + lane;          \
    float ax = tb[3 * mA], ay = tb[3 * mA + 1], az = tb[3 * mA + 2];     \
    float bx = tb[3 * mB], by = tb[3 * mB + 1], bz = tb[3 * mB + 2];     \
    T0_##j = vf2{ax, bx};                                                \
    T1_##j = vf2{ay, by};                                                \
    T2_##j = vf2{az, bz};                                                \
    TY_##j = vf2{fmaf(ax, ax, fmaf(ay, ay, az * az)),                    \
                 fmaf(bx, bx, fmaf(by, by, bz * bz))};                   \
  }
#define PAIRC(j, acc)                                                    \
  {                                                                      \
    vf2 s = __builtin_elementwise_fma(Q0, T0_##j, TY_##j);               \
    s = __builtin_elementwise_fma(Q1, T1_##j, s);                        \
    s = __builtin_elementwise_fma(Q2, T2_##j, s);                        \
    acc = fminf(fminf(s.x, s.y), acc); /* v_min3_f32 */                  \
  }

__global__ __launch_bounds__(256, 4) void chamfer_main(
    const float* __restrict__ pred, const float* __restrict__ target,
    const int* __restrict__ idx, unsigned* __restrict__ wsmin) {
  __shared__ float qs0[64], qs1[64], qs2[64], qw[64];  // SoA query records
  const int lane = threadIdx.x & 63;
  const int w = blockIdx.x * 4 + (threadIdx.x >> 6);  // 0..4095
  const int b = w >> 11;
  const int rem = w & 2047;
  const int tch = rem & (TCH - 1);  // varies across block's 4 waves
  const int qg = rem >> 5;          // uniform across block (4 | TCH)

  // Gather this block's query group directly from pred[idx] (L2-hot).
  if (threadIdx.x < 64) {
    int s = qg * 64 + threadIdx.x;
    int i = idx[s];
    const float* p = pred + ((size_t)b * N + (size_t)i) * 3;
    float x = p[0], y = p[1], z = p[2];
    qs0[threadIdx.x] = -2.0f * x;
    qs1[threadIdx.x] = -2.0f * y;
    qs2[threadIdx.x] = -2.0f * z;
    qw[threadIdx.x] = x * x + y * y + z * z;
  }

  // Stage this lane's 16 targets into NAMED registers (8 float2-pairs).
  const float* tb = target + ((size_t)b * M + (size_t)tch * WT) * 3;
  DECLP(0) DECLP(1) DECLP(2) DECLP(3) DECLP(4) DECLP(5) DECLP(6) DECLP(7)
  LOADP(0) LOADP(1) LOADP(2) LOADP(3) LOADP(4) LOADP(5) LOADP(6) LOADP(7)
  __syncthreads();

  const float qx2_home = qw[lane];        // own |x|^2, applied at the end
  const int rot = ((lane + 1) & 63) * 4;  // bpermute byte-addr: pull lane+1
  float mm = INFINITY;                    // traveling min of (|y|^2 - 2x.y)
  int qoff = lane;
  float q0 = qs0[qoff], q1 = qs1[qoff], q2 = qs2[qoff];

#pragma unroll 1  // keep the 32 vf2 target regs' live ranges tight
  for (int step = 0; step < 64; ++step) {
    // Prefetch next query (LDS latency hides under the 8-pair compute).
    int qn = (qoff + 1) & 63;
    float n0 = qs0[qn], n1 = qs1[qn], n2 = qs2[qn];
    vf2 Q0 = vf2{q0, q0}, Q1 = vf2{q1, q1}, Q2 = vf2{q2, q2};
    float m0 = INFINITY, m1 = INFINITY;
    PAIRC(0, m0) PAIRC(1, m1) PAIRC(2, m0) PAIRC(3, m1)
    PAIRC(4, m0) PAIRC(5, m1) PAIRC(6, m0) PAIRC(7, m1)
    // Incoming traveling min (prev step's bpermute) consumed only here.
    mm = fminf(mm, fminf(m0, m1));
    mm = __int_as_float(__builtin_amdgcn_ds_bpermute(rot, __float_as_int(mm)));
    q0 = n0; q1 = n1; q2 = n2; qoff = qn;
  }
  // After 64 rotations the own query's complete chunk-min is back home.
  const int q = b * S + qg * 64 + lane;
  atomicMin(&wsmin[q], __float_as_uint(fmaxf(qx2_home + mm, 0.0f)));
}

__global__ __launch_bounds__(1024) void chamfer_finish(
    const unsigned* __restrict__ wsmin, float* __restrict__ out) {
  __shared__ float red[16];
  float sum = 0.0f;
#pragma unroll
  for (int i = 0; i < QTOT / 1024; ++i)
    sum += sqrtf(__uint_as_float(wsmin[threadIdx.x + i * 1024]));
#pragma unroll
  for (int off = 32; off > 0; off >>= 1)
    sum += __shfl_down(sum, off, 64);
  int wv = threadIdx.x >> 6;
  if ((threadIdx.x & 63) == 0) red[wv] = sum;
  __syncthreads();
  if (threadIdx.x == 0) {
    float t = 0.0f;
#pragma unroll
    for (int i = 0; i < 16; ++i) t += red[i];
    out[0] = t / (float)QTOT;
  }
}

extern "C" void kernel_launch(void* const* d_in, const int* in_sizes, int n_in,
                              void* d_out, int out_size, void* d_ws, size_t ws_size,
                              hipStream_t stream) {
  const float* pred = (const float*)d_in[0];
  const float* target = (const float*)d_in[1];
  const int* idx = (const int*)d_in[2];
  unsigned* wsmin = (unsigned*)d_ws;

  hipMemsetAsync(wsmin, 0xFF, QTOT * sizeof(unsigned), stream);
  chamfer_main<<<BLOCKS, 256, 0, stream>>>(pred, target, idx, wsmin);
  chamfer_finish<<<1, 1024, 0, stream>>>(wsmin, (float*)d_out);
}